// Round 6
// baseline (267.078 us; speedup 1.0000x reference)
//
#include <hip/hip_runtime.h>
#include <hip/hip_bf16.h>

#define D 64
#define ED 32
#define NN 50000
#define EE 800000

typedef __attribute__((ext_vector_type(8))) short bf16x8;
typedef __attribute__((ext_vector_type(4))) float f32x4;

__device__ __forceinline__ short f2bf(float f) {
    __hip_bfloat16 h = __float2bfloat16(f);
    return *reinterpret_cast<short*>(&h);
}
__device__ __forceinline__ float bfhi2f(unsigned w) { return __uint_as_float(w & 0xFFFF0000u); }
__device__ __forceinline__ float bflo2f(unsigned w) { return __uint_as_float(w << 16); }
__device__ __forceinline__ unsigned packqv(float q, float v) {
    return (unsigned)(unsigned short)f2bf(q) | ((unsigned)(unsigned short)f2bf(v) << 16);
}
__device__ __forceinline__ float rl(float v, int l) {
    return __int_as_float(__builtin_amdgcn_readlane(__float_as_int(v), l));
}

// Pre-pack edge-weight B-fragments, transposed: WgT[c][k]=bf16(WkE+WqE), WvT[c][k]=bf16(WvE)
__global__ void prep_wfrag(const float* __restrict__ Wk, const float* __restrict__ Wq,
                           const float* __restrict__ Wv,
                           unsigned short* __restrict__ WgT, unsigned short* __restrict__ WvT) {
    const int i = blockIdx.x * 256 + threadIdx.x;
    if (i < D * ED) {
        const int c = i >> 5, k = i & 31;
        const size_t off = (size_t)(D + k) * D + c;
        WgT[i] = (unsigned short)f2bf(Wk[off] + Wq[off]);
        WvT[i] = (unsigned short)f2bf(Wv[off]);
    }
}

// ---- CSR build: histogram -> exclusive scan (3 kernels) -> scatter-permute ----
__global__ void k_hist(const int* __restrict__ dstI, int* __restrict__ deg) {
    const int e = blockIdx.x * 256 + threadIdx.x;
    if (e < EE) atomicAdd(&deg[dstI[e]], 1);
}

__global__ void k_scanA(const int* __restrict__ deg, int* __restrict__ off,
                        int* __restrict__ bsum) {
    __shared__ int tmp[256];
    const int t = threadIdx.x, i = blockIdx.x * 256 + t;
    const int v = (i < NN) ? deg[i] : 0;
    tmp[t] = v;
    __syncthreads();
    for (int d = 1; d < 256; d <<= 1) {
        const int add = (t >= d) ? tmp[t - d] : 0;
        __syncthreads();
        tmp[t] += add;
        __syncthreads();
    }
    if (i < NN) off[i] = tmp[t] - v;          // exclusive
    if (t == 255) bsum[blockIdx.x] = tmp[255];
}

__global__ void k_scanB(int* __restrict__ bsum, int nb) {
    __shared__ int tmp[256];
    const int t = threadIdx.x;
    const int v = (t < nb) ? bsum[t] : 0;
    tmp[t] = v;
    __syncthreads();
    for (int d = 1; d < 256; d <<= 1) {
        const int add = (t >= d) ? tmp[t - d] : 0;
        __syncthreads();
        tmp[t] += add;
        __syncthreads();
    }
    if (t < nb) bsum[t] = tmp[t] - v;         // exclusive, in place
}

__global__ void k_scanC(int* __restrict__ off, const int* __restrict__ bsum) {
    const int i = blockIdx.x * 256 + threadIdx.x;
    if (i < NN) off[i] += bsum[blockIdx.x];
}

// consumes off (atomicAdd); afterwards off[n] == end of run n (start = off[n-1])
__global__ void k_scatter(const int* __restrict__ srcI, const int* __restrict__ dstI,
                          int* __restrict__ off,
                          int* __restrict__ sortedSrc, int* __restrict__ perm) {
    const int e = blockIdx.x * 256 + threadIdx.x;
    if (e < EE) {
        const int d = dstI[e];
        const int p = atomicAdd(&off[d], 1);
        sortedSrc[p] = srcI[e];
        perm[p] = e;
    }
}

// Node kernel A: kx = x@Wk[:D] + bk (f32) ; out = x@Wskip + bias (initializes out)
__global__ __launch_bounds__(256, 3)
void node_ks(const float* __restrict__ x,
             const float* __restrict__ Wk, const float* __restrict__ bk,
             const float* __restrict__ Ws, const float* __restrict__ bias,
             float* __restrict__ kx, float* __restrict__ out, int nWaves) {
    const int lane = threadIdx.x & 63;
    const int wid  = blockIdx.x * 4 + (threadIdx.x >> 6);
    float wk[D], ws[D];
#pragma unroll
    for (int c = 0; c < D; ++c) {
        wk[c] = Wk[c * D + lane];
        ws[c] = Ws[c * D + lane];
    }
    const float bkv = bk[lane], bsv = bias[lane];
    for (int n = wid; n < NN; n += nWaves) {
        const float xv = x[(size_t)n * D + lane];
        float aK = bkv, aS = bsv;
#pragma unroll
        for (int c = 0; c < D; ++c) {
            const float a = rl(xv, c);
            aK = fmaf(a, wk[c], aK);
            aS = fmaf(a, ws[c], aS);
        }
        kx[(size_t)n * D + lane]  = aK;
        out[(size_t)n * D + lane] = aS;
    }
}

// Node kernel B: qv[n][c] = pack(bf16(x@Wq+bq), bf16(x@Wv+bv))
__global__ __launch_bounds__(256, 3)
void node_qv(const float* __restrict__ x,
             const float* __restrict__ Wq, const float* __restrict__ bq,
             const float* __restrict__ Wv, const float* __restrict__ bv,
             unsigned* __restrict__ qv, int nWaves) {
    const int lane = threadIdx.x & 63;
    const int wid  = blockIdx.x * 4 + (threadIdx.x >> 6);
    float wq[D], wv[D];
#pragma unroll
    for (int c = 0; c < D; ++c) {
        wq[c] = Wq[c * D + lane];
        wv[c] = Wv[c * D + lane];
    }
    const float bqv = bq[lane], bvv = bv[lane];
    for (int n = wid; n < NN; n += nWaves) {
        const float xv = x[(size_t)n * D + lane];
        float aQ = bqv, aV = bvv;
#pragma unroll
        for (int c = 0; c < D; ++c) {
            const float a = rl(xv, c);
            aQ = fmaf(a, wq[c], aQ);
            aV = fmaf(a, wv[c], aV);
        }
        qv[(size_t)n * D + lane] = packqv(aQ, aV);
    }
}

// Node-centric aggregation: one wave per dst node, 16-edge MFMA chunks,
// in-register segment reduce, NO f32 atomics.
__global__ __launch_bounds__(256, 4)
void agg_csr(const int* __restrict__ offEnd, const int* __restrict__ sortedSrc,
             const int* __restrict__ perm, const float* __restrict__ ea,
             const unsigned short* __restrict__ WgT, const unsigned short* __restrict__ WvT,
             const float* __restrict__ kx, const unsigned* __restrict__ qv,
             float* __restrict__ out) {
    const int lane = threadIdx.x & 63;
    const int node = blockIdx.x * 4 + (threadIdx.x >> 6);
    if (node >= NN) return;
    const int lg = lane >> 4;       // k-block (A,B) / row-group (C)
    const int lr = lane & 15;       // row (A) / col (B, C)
    const int start = (node == 0) ? 0 : offEnd[node - 1];
    const int end   = offEnd[node];
    if (start == end) return;       // out already holds skip+bias

    bf16x8 bg[4], bvf[4];
#pragma unroll
    for (int h = 0; h < 4; ++h) {
        bg[h]  = *(const bf16x8*)(WgT + (size_t)(16 * h + lr) * ED + 8 * lg);
        bvf[h] = *(const bf16x8*)(WvT + (size_t)(16 * h + lr) * ED + 8 * lg);
    }
    float kxv[4];
#pragma unroll
    for (int h = 0; h < 4; ++h) kxv[h] = kx[(size_t)node * D + 16 * h + lr];

    float colSum[4] = {0.f, 0.f, 0.f, 0.f};

    for (int s = start; s < end; s += 16) {
        const int dc = end - s < 16 ? end - s : 16;   // chunk size, wave-uniform
        // A-frag: row lr -> sorted edge s+lr (zero-padded past dc)
        bf16x8 af = (bf16x8)0;
        if (lr < dc) {
            const int pe = __builtin_nontemporal_load(perm + s + lr);
            const float* ap = ea + (size_t)pe * ED + 8 * lg;
            const f32x4 a0 = __builtin_nontemporal_load((const f32x4*)ap);
            const f32x4 a1 = __builtin_nontemporal_load((const f32x4*)(ap + 4));
#pragma unroll
            for (int e2 = 0; e2 < 4; ++e2) { af[e2] = f2bf(a0[e2]); af[e2 + 4] = f2bf(a1[e2]); }
        }
        // srcs for this lane's 4 C-rows (edges s + 4*lg + r)
        int srcr[4];
#pragma unroll
        for (int r = 0; r < 4; ++r) {
            const int j = 4 * lg + r;
            srcr[r] = (j < dc) ? __builtin_nontemporal_load(sortedSrc + s + j) : 0;
        }
        // hoisted qv gathers (16 independent loads in flight)
        unsigned qg[4][4];
#pragma unroll
        for (int r = 0; r < 4; ++r) {
            const unsigned* qp = qv + (size_t)srcr[r] * D;
#pragma unroll
            for (int h = 0; h < 4; ++h) qg[r][h] = qp[16 * h + lr];
        }
        // MFMAs (all lanes converged here)
        f32x4 accG[4], accV[4];
#pragma unroll
        for (int h = 0; h < 4; ++h) {
            accG[h] = __builtin_amdgcn_mfma_f32_16x16x32_bf16(af, bg[h],  (f32x4)(0.f), 0, 0, 0);
            accV[h] = __builtin_amdgcn_mfma_f32_16x16x32_bf16(af, bvf[h], (f32x4)(0.f), 0, 0, 0);
        }
        // gate + masked in-lane accumulate over this lane's 4 rows
#pragma unroll
        for (int r = 0; r < 4; ++r) {
            const bool valid = (4 * lg + r) < dc;
#pragma unroll
            for (int h = 0; h < 4; ++h) {
                const float z = accG[h][r] + kxv[h] + bflo2f(qg[r][h]);
                const float v = accV[h][r] + bfhi2f(qg[r][h]);
                const float m = v * __builtin_amdgcn_rcpf(1.0f + __expf(-z));
                colSum[h] += valid ? m : 0.f;
            }
        }
    }
    // cross-lane reduce over the 4 row-groups (lanes differing in bits 4,5)
#pragma unroll
    for (int h = 0; h < 4; ++h) {
        colSum[h] += __shfl_xor(colSum[h], 16, 64);
        colSum[h] += __shfl_xor(colSum[h], 32, 64);
    }
    if (lg == 0) {
#pragma unroll
        for (int h = 0; h < 4; ++h)
            out[(size_t)node * D + 16 * h + lr] += colSum[h];
    }
}

extern "C" void kernel_launch(void* const* d_in, const int* in_sizes, int n_in,
                              void* d_out, int out_size, void* d_ws, size_t ws_size,
                              hipStream_t stream) {
    const float* x    = (const float*)d_in[0];
    const int*   eidx = (const int*)d_in[1];      // [2, E]: row0=src, row1=dst
    const float* eatt = (const float*)d_in[2];
    const float* Wk   = (const float*)d_in[3];
    const float* bk   = (const float*)d_in[4];
    const float* Wq   = (const float*)d_in[5];
    const float* bq   = (const float*)d_in[6];
    const float* Wv   = (const float*)d_in[7];
    const float* bv   = (const float*)d_in[8];
    const float* Ws   = (const float*)d_in[9];
    const float* bias = (const float*)d_in[10];
    float* out = (float*)d_out;

    // workspace carve (all offsets 16B-aligned)
    char* w = (char*)d_ws;
    float*    kx  = (float*)w;            w += (size_t)NN * D * 4;   // 12.8 MB
    unsigned* qv  = (unsigned*)w;         w += (size_t)NN * D * 4;   // 12.8 MB
    unsigned short* WgT = (unsigned short*)w;  w += D * ED * 2;      // 4 KB
    unsigned short* WvT = (unsigned short*)w;  w += D * ED * 2;      // 4 KB
    int* deg  = (int*)w;                  w += (size_t)NN * 4;       // 200 KB
    int* off  = (int*)w;                  w += (size_t)NN * 4;       // 200 KB
    int* bsum = (int*)w;                  w += 256 * 4;              // 1 KB
    int* sortedSrc = (int*)w;             w += (size_t)EE * 4;       // 3.2 MB
    int* perm = (int*)w;                  /* 3.2 MB */

    const int* srcI = eidx;
    const int* dstI = eidx + EE;

    const int NB = (NN + 255) / 256;   // 196

    prep_wfrag<<<(D * ED + 255) / 256, 256, 0, stream>>>(Wk, Wq, Wv, WgT, WvT);

    // CSR build
    hipMemsetAsync(deg, 0, (size_t)NN * 4, stream);
    k_hist<<<EE / 256, 256, 0, stream>>>(dstI, deg);
    k_scanA<<<NB, 256, 0, stream>>>(deg, off, bsum);
    k_scanB<<<1, 256, 0, stream>>>(bsum, NB);
    k_scanC<<<NB, 256, 0, stream>>>(off, bsum);
    k_scatter<<<EE / 256, 256, 0, stream>>>(srcI, dstI, off, sortedSrc, perm);

    // node transforms
    const int nodeBlocks = 512;
    const int nodeWaves  = nodeBlocks * 4;
    node_ks<<<nodeBlocks, 256, 0, stream>>>(x, Wk, bk, Ws, bias, kx, out, nodeWaves);
    node_qv<<<nodeBlocks, 256, 0, stream>>>(x, Wq, bq, Wv, bv, qv, nodeWaves);

    // node-centric aggregation: one wave per node
    agg_csr<<<(NN + 3) / 4, 256, 0, stream>>>(off, sortedSrc, perm, eatt,
                                              WgT, WvT, kx, qv, out);
}

// Round 7
// 223.751 us; speedup vs baseline: 1.1936x; 1.1936x over previous
//
#include <hip/hip_runtime.h>
#include <hip/hip_bf16.h>

#define D 64
#define ED 32
#define NN 50000
#define EE 800000
#define NT64 (EE / 64)   // 12500 64-edge tiles, exact

typedef __attribute__((ext_vector_type(8))) short bf16x8;
typedef __attribute__((ext_vector_type(4))) float f32x4;
typedef __attribute__((ext_vector_type(4))) unsigned uint4v;

__device__ __forceinline__ short f2bf(float f) {
    __hip_bfloat16 h = __float2bfloat16(f);
    return *reinterpret_cast<short*>(&h);
}
__device__ __forceinline__ float bfhi2f(unsigned w) { return __uint_as_float(w & 0xFFFF0000u); }
__device__ __forceinline__ float bflo2f(unsigned w) { return __uint_as_float(w << 16); }
__device__ __forceinline__ unsigned packqv(float q, float v) {
    return (unsigned)(unsigned short)f2bf(q) | ((unsigned)(unsigned short)f2bf(v) << 16);
}
__device__ __forceinline__ float rl(float v, int l) {
    return __int_as_float(__builtin_amdgcn_readlane(__float_as_int(v), l));
}

// Pre-pack edge-weight B-fragments, transposed: WgT[c][k]=bf16(WkE+WqE), WvT[c][k]=bf16(WvE)
__global__ void prep_wfrag(const float* __restrict__ Wk, const float* __restrict__ Wq,
                           const float* __restrict__ Wv,
                           unsigned short* __restrict__ WgT, unsigned short* __restrict__ WvT) {
    const int i = blockIdx.x * 256 + threadIdx.x;
    if (i < D * ED) {
        const int c = i >> 5, k = i & 31;
        const size_t off = (size_t)(D + k) * D + c;
        WgT[i] = (unsigned short)f2bf(Wk[off] + Wq[off]);
        WvT[i] = (unsigned short)f2bf(Wv[off]);
    }
}

// ---- CSR-order build: histogram -> exclusive scan -> scatter (rec = src|dst<<16, perm) ----
__global__ void k_hist(const int* __restrict__ dstI, int* __restrict__ deg) {
    const int e = blockIdx.x * 256 + threadIdx.x;
    if (e < EE) atomicAdd(&deg[dstI[e]], 1);
}

__global__ void k_scanA(const int* __restrict__ deg, int* __restrict__ off,
                        int* __restrict__ bsum) {
    __shared__ int tmp[256];
    const int t = threadIdx.x, i = blockIdx.x * 256 + t;
    const int v = (i < NN) ? deg[i] : 0;
    tmp[t] = v;
    __syncthreads();
    for (int d = 1; d < 256; d <<= 1) {
        const int add = (t >= d) ? tmp[t - d] : 0;
        __syncthreads();
        tmp[t] += add;
        __syncthreads();
    }
    if (i < NN) off[i] = tmp[t] - v;          // exclusive
    if (t == 255) bsum[blockIdx.x] = tmp[255];
}

__global__ void k_scanB(int* __restrict__ bsum, int nb) {
    __shared__ int tmp[256];
    const int t = threadIdx.x;
    const int v = (t < nb) ? bsum[t] : 0;
    tmp[t] = v;
    __syncthreads();
    for (int d = 1; d < 256; d <<= 1) {
        const int add = (t >= d) ? tmp[t - d] : 0;
        __syncthreads();
        tmp[t] += add;
        __syncthreads();
    }
    if (t < nb) bsum[t] = tmp[t] - v;         // exclusive, in place
}

__global__ void k_scanC(int* __restrict__ off, const int* __restrict__ bsum) {
    const int i = blockIdx.x * 256 + threadIdx.x;
    if (i < NN) off[i] += bsum[blockIdx.x];
}

// rec[p] = perm<<32 | src | dst<<16  (node ids < 65536, so 16 bits each)
__global__ void k_scatter(const int* __restrict__ srcI, const int* __restrict__ dstI,
                          int* __restrict__ off, unsigned long long* __restrict__ rec) {
    const int e = blockIdx.x * 256 + threadIdx.x;
    if (e < EE) {
        const int s = srcI[e], d = dstI[e];
        const int p = atomicAdd(&off[d], 1);
        rec[p] = ((unsigned long long)(unsigned)e << 32)
               | (unsigned)(s | (d << 16));
    }
}

// Node kernel A: kx = x@Wk[:D] + bk (f32) ; out = x@Wskip + bias (initializes out)
__global__ __launch_bounds__(256, 3)
void node_ks(const float* __restrict__ x,
             const float* __restrict__ Wk, const float* __restrict__ bk,
             const float* __restrict__ Ws, const float* __restrict__ bias,
             float* __restrict__ kx, float* __restrict__ out, int nWaves) {
    const int lane = threadIdx.x & 63;
    const int wid  = blockIdx.x * 4 + (threadIdx.x >> 6);
    float wk[D], ws[D];
#pragma unroll
    for (int c = 0; c < D; ++c) {
        wk[c] = Wk[c * D + lane];
        ws[c] = Ws[c * D + lane];
    }
    const float bkv = bk[lane], bsv = bias[lane];
    for (int n = wid; n < NN; n += nWaves) {
        const float xv = x[(size_t)n * D + lane];
        float aK = bkv, aS = bsv;
#pragma unroll
        for (int c = 0; c < D; ++c) {
            const float a = rl(xv, c);
            aK = fmaf(a, wk[c], aK);
            aS = fmaf(a, ws[c], aS);
        }
        kx[(size_t)n * D + lane]  = aK;
        out[(size_t)n * D + lane] = aS;
    }
}

// Node kernel B: qv[n][c] = pack(bf16(x@Wq+bq), bf16(x@Wv+bv))
__global__ __launch_bounds__(256, 3)
void node_qv(const float* __restrict__ x,
             const float* __restrict__ Wq, const float* __restrict__ bq,
             const float* __restrict__ Wv, const float* __restrict__ bv,
             unsigned* __restrict__ qv, int nWaves) {
    const int lane = threadIdx.x & 63;
    const int wid  = blockIdx.x * 4 + (threadIdx.x >> 6);
    float wq[D], wv[D];
#pragma unroll
    for (int c = 0; c < D; ++c) {
        wq[c] = Wq[c * D + lane];
        wv[c] = Wv[c * D + lane];
    }
    const float bqv = bq[lane], bvv = bv[lane];
    for (int n = wid; n < NN; n += nWaves) {
        const float xv = x[(size_t)n * D + lane];
        float aQ = bqv, aV = bvv;
#pragma unroll
        for (int c = 0; c < D; ++c) {
            const float a = rl(xv, c);
            aQ = fmaf(a, wq[c], aQ);
            aV = fmaf(a, wv[c], aV);
        }
        qv[(size_t)n * D + lane] = packqv(aQ, aV);
    }
}

// Edge-parallel aggregation over dst-SORTED edges: 64 edges per wave,
// in-wave segmented reduction -> ~1 atomic bundle per dst-run (not per edge).
__global__ __launch_bounds__(256, 3)
void agg_sorted(const unsigned* __restrict__ rec, const float* __restrict__ ea,
                const unsigned short* __restrict__ WgT, const unsigned short* __restrict__ WvT,
                const float* __restrict__ kx, const unsigned* __restrict__ qv,
                float* __restrict__ out) {
    const int lane = threadIdx.x & 63;
    const int wid  = blockIdx.x * 4 + (threadIdx.x >> 6);   // tile id, grid exact
    const int lg = lane >> 4;       // k-block (A,B) / row-group (C)
    const int lr = lane & 15;       // row (A) / col (B, C)
    const int e0 = wid * 64;

    bf16x8 bg[4], bvf[4];
#pragma unroll
    for (int h = 0; h < 4; ++h) {
        bg[h]  = *(const bf16x8*)(WgT + (size_t)(16 * h + lr) * ED + 8 * lg);
        bvf[h] = *(const bf16x8*)(WvT + (size_t)(16 * h + lr) * ED + 8 * lg);
    }

#pragma unroll
    for (int g = 0; g < 4; ++g) {
        const int gb = e0 + 16 * g;
        // lane's 4 C-rows = sorted edges gb+4*lg .. +3 ; 32B contiguous rec load
        const uint4v rA = *(const uint4v*)(rec + 2 * (gb + 4 * lg));
        const uint4v rB = *(const uint4v*)(rec + 2 * (gb + 4 * lg) + 4);
        int dR[4], sR[4];
        dR[0] = (int)(rA.x >> 16); sR[0] = (int)(rA.x & 0xFFFFu);
        dR[1] = (int)(rA.z >> 16); sR[1] = (int)(rA.z & 0xFFFFu);
        dR[2] = (int)(rB.x >> 16); sR[2] = (int)(rB.x & 0xFFFFu);
        dR[3] = (int)(rB.z >> 16); sR[3] = (int)(rB.z & 0xFFFFu);

        // A-frag: row lr -> original edge rec[gb+lr].perm ; ea row streamed (NT)
        const unsigned pl = rec[2 * (gb + lr) + 1];
        const float* ap = ea + (size_t)pl * ED + 8 * lg;
        const f32x4 a0 = __builtin_nontemporal_load((const f32x4*)ap);
        const f32x4 a1 = __builtin_nontemporal_load((const f32x4*)(ap + 4));

        // hoisted gathers: 16 qv (random src) + 16 kx (run-local, L1-friendly)
        unsigned qg[4][4];
        float    kk[4][4];
#pragma unroll
        for (int r = 0; r < 4; ++r) {
            const unsigned* qp = qv + (size_t)sR[r] * D;
            const float*    kp = kx + (size_t)dR[r] * D;
#pragma unroll
            for (int h = 0; h < 4; ++h) {
                qg[r][h] = qp[16 * h + lr];
                kk[r][h] = kp[16 * h + lr];
            }
        }

        bf16x8 af;
#pragma unroll
        for (int e2 = 0; e2 < 4; ++e2) { af[e2] = f2bf(a0[e2]); af[e2 + 4] = f2bf(a1[e2]); }

        f32x4 accG[4], accV[4];
#pragma unroll
        for (int h = 0; h < 4; ++h) {
            accG[h] = __builtin_amdgcn_mfma_f32_16x16x32_bf16(af, bg[h],  (f32x4)(0.f), 0, 0, 0);
            accV[h] = __builtin_amdgcn_mfma_f32_16x16x32_bf16(af, bvf[h], (f32x4)(0.f), 0, 0, 0);
        }

        // messages in C layout
        float msg[4][4];
#pragma unroll
        for (int r = 0; r < 4; ++r)
#pragma unroll
            for (int h = 0; h < 4; ++h) {
                const float z = accG[h][r] + kk[r][h] + bflo2f(qg[r][h]);
                const float v = accV[h][r] + bfhi2f(qg[r][h]);
                msg[r][h] = v * __builtin_amdgcn_rcpf(1.0f + __expf(-z));
            }

        // segmented reduce: iterate dst-runs (sorted ascending within group)
        bool done[4] = {false, false, false, false};
        while (true) {
            int m0 = 0x7FFFFFFF;
#pragma unroll
            for (int r = 0; r < 4; ++r) m0 = min(m0, done[r] ? 0x7FFFFFFF : dR[r]);
            m0 = min(m0, __shfl_xor(m0, 16, 64));
            m0 = min(m0, __shfl_xor(m0, 32, 64));
            if (m0 == 0x7FFFFFFF) break;          // wave-uniform exit
            float sh[4];
#pragma unroll
            for (int h = 0; h < 4; ++h) {
                float a = 0.f;
#pragma unroll
                for (int r = 0; r < 4; ++r) a += (dR[r] == m0) ? msg[r][h] : 0.f;
                a += __shfl_xor(a, 16, 64);
                a += __shfl_xor(a, 32, 64);
                sh[h] = a;
            }
#pragma unroll
            for (int r = 0; r < 4; ++r) done[r] = done[r] || (dR[r] == m0);
            if (lane < 16) {
                float* op = out + (size_t)m0 * D;
#pragma unroll
                for (int h = 0; h < 4; ++h)
                    unsafeAtomicAdd(&op[16 * h + lane], sh[h]);
            }
        }
    }
}

extern "C" void kernel_launch(void* const* d_in, const int* in_sizes, int n_in,
                              void* d_out, int out_size, void* d_ws, size_t ws_size,
                              hipStream_t stream) {
    const float* x    = (const float*)d_in[0];
    const int*   eidx = (const int*)d_in[1];      // [2, E]: row0=src, row1=dst
    const float* eatt = (const float*)d_in[2];
    const float* Wk   = (const float*)d_in[3];
    const float* bk   = (const float*)d_in[4];
    const float* Wq   = (const float*)d_in[5];
    const float* bq   = (const float*)d_in[6];
    const float* Wv   = (const float*)d_in[7];
    const float* bv   = (const float*)d_in[8];
    const float* Ws   = (const float*)d_in[9];
    const float* bias = (const float*)d_in[10];
    float* out = (float*)d_out;

    // workspace carve (offsets keep 16B alignment)
    char* w = (char*)d_ws;
    float*    kx  = (float*)w;            w += (size_t)NN * D * 4;   // 12.8 MB
    unsigned* qv  = (unsigned*)w;         w += (size_t)NN * D * 4;   // 12.8 MB
    unsigned short* WgT = (unsigned short*)w;  w += D * ED * 2;      // 4 KB
    unsigned short* WvT = (unsigned short*)w;  w += D * ED * 2;      // 4 KB
    int* deg  = (int*)w;                  w += (size_t)NN * 4;       // 200 KB
    int* off  = (int*)w;                  w += (size_t)NN * 4;       // 200 KB
    int* bsum = (int*)w;                  w += 256 * 4;              // 1 KB
    unsigned long long* rec = (unsigned long long*)w;                // 6.4 MB

    const int* srcI = eidx;
    const int* dstI = eidx + EE;
    const int NB = (NN + 255) / 256;   // 196

    prep_wfrag<<<(D * ED + 255) / 256, 256, 0, stream>>>(Wk, Wq, Wv, WgT, WvT);

    // CSR-order build
    hipMemsetAsync(deg, 0, (size_t)NN * 4, stream);
    k_hist<<<EE / 256, 256, 0, stream>>>(dstI, deg);
    k_scanA<<<NB, 256, 0, stream>>>(deg, off, bsum);
    k_scanB<<<1, 256, 0, stream>>>(bsum, NB);
    k_scanC<<<NB, 256, 0, stream>>>(off, bsum);
    k_scatter<<<EE / 256, 256, 0, stream>>>(srcI, dstI, off, rec);

    // node transforms
    const int nodeBlocks = 512;
    const int nodeWaves  = nodeBlocks * 4;
    node_ks<<<nodeBlocks, 256, 0, stream>>>(x, Wk, bk, Ws, bias, kx, out, nodeWaves);
    node_qv<<<nodeBlocks, 256, 0, stream>>>(x, Wq, bq, Wv, bv, qv, nodeWaves);

    // edge-parallel aggregation over sorted records: 12500 waves = 3125 blocks
    agg_sorted<<<NT64 / 4, 256, 0, stream>>>((const unsigned*)rec, eatt,
                                             WgT, WvT, kx, qv, out);
}

// Round 8
// 190.889 us; speedup vs baseline: 1.3991x; 1.1722x over previous
//
#include <hip/hip_runtime.h>
#include <hip/hip_bf16.h>

#define D 64
#define ED 32
#define NN 50000
#define EE 800000
#define NT64 (EE / 64)   // 12500 64-edge tiles, exact
#define NWN (NN / 16)    // 3125 16-node tiles, exact

typedef __attribute__((ext_vector_type(8))) short bf16x8;
typedef __attribute__((ext_vector_type(4))) float f32x4;
typedef __attribute__((ext_vector_type(4))) unsigned uint4v;

__device__ __forceinline__ short f2bf(float f) {
    __hip_bfloat16 h = __float2bfloat16(f);
    return *reinterpret_cast<short*>(&h);
}
__device__ __forceinline__ float bfhi2f(unsigned w) { return __uint_as_float(w & 0xFFFF0000u); }
__device__ __forceinline__ float bflo2f(unsigned w) { return __uint_as_float(w << 16); }
__device__ __forceinline__ unsigned packqv(float q, float v) {
    return (unsigned)(unsigned short)f2bf(q) | ((unsigned)(unsigned short)f2bf(v) << 16);
}

// Merged weight prep:
//  WnT[m][col][k] = bf16 of node-part W (m: 0=Wskip,1=Wk,2=Wq,3=Wv), 4*64*64
//  WgT[col][k] = bf16(WkE+WqE), WvT[col][k] = bf16(WvE)  (edge parts, 64*32 each)
__global__ void prep_w(const float* __restrict__ Wk, const float* __restrict__ Wq,
                       const float* __restrict__ Wv, const float* __restrict__ Ws,
                       unsigned short* __restrict__ WnT,
                       unsigned short* __restrict__ WgT, unsigned short* __restrict__ WvT) {
    const int i = blockIdx.x * 256 + threadIdx.x;
    if (i < 4 * D * D) {
        const int m = i >> 12, col = (i >> 6) & 63, k = i & 63;
        const float* W = (m == 0) ? Ws : (m == 1) ? Wk : (m == 2) ? Wq : Wv;
        WnT[i] = (unsigned short)f2bf(W[k * D + col]);
    } else {
        const int j = i - 4 * D * D;
        if (j < D * ED) {
            const int c = j >> 5, k = j & 31;
            const size_t off = (size_t)(D + k) * D + c;
            WgT[j] = (unsigned short)f2bf(Wk[off] + Wq[off]);
            WvT[j] = (unsigned short)f2bf(Wv[off]);
        }
    }
}

// ---- CSR-order build: histogram -> exclusive scan -> scatter (unchanged, proven) ----
__global__ void k_hist(const int* __restrict__ dstI, int* __restrict__ deg) {
    const int e = blockIdx.x * 256 + threadIdx.x;
    if (e < EE) atomicAdd(&deg[dstI[e]], 1);
}

__global__ void k_scanA(const int* __restrict__ deg, int* __restrict__ off,
                        int* __restrict__ bsum) {
    __shared__ int tmp[256];
    const int t = threadIdx.x, i = blockIdx.x * 256 + t;
    const int v = (i < NN) ? deg[i] : 0;
    tmp[t] = v;
    __syncthreads();
    for (int d = 1; d < 256; d <<= 1) {
        const int add = (t >= d) ? tmp[t - d] : 0;
        __syncthreads();
        tmp[t] += add;
        __syncthreads();
    }
    if (i < NN) off[i] = tmp[t] - v;          // exclusive
    if (t == 255) bsum[blockIdx.x] = tmp[255];
}

__global__ void k_scanB(int* __restrict__ bsum, int nb) {
    __shared__ int tmp[256];
    const int t = threadIdx.x;
    const int v = (t < nb) ? bsum[t] : 0;
    tmp[t] = v;
    __syncthreads();
    for (int d = 1; d < 256; d <<= 1) {
        const int add = (t >= d) ? tmp[t - d] : 0;
        __syncthreads();
        tmp[t] += add;
        __syncthreads();
    }
    if (t < nb) bsum[t] = tmp[t] - v;         // exclusive, in place
}

__global__ void k_scanC(int* __restrict__ off, const int* __restrict__ bsum) {
    const int i = blockIdx.x * 256 + threadIdx.x;
    if (i < NN) off[i] += bsum[blockIdx.x];
}

// rec[p] = perm<<32 | src | dst<<16  (node ids < 65536)
__global__ void k_scatter(const int* __restrict__ srcI, const int* __restrict__ dstI,
                          int* __restrict__ off, unsigned long long* __restrict__ rec) {
    const int e = blockIdx.x * 256 + threadIdx.x;
    if (e < EE) {
        const int s = srcI[e], d = dstI[e];
        const int p = atomicAdd(&off[d], 1);
        rec[p] = ((unsigned long long)(unsigned)e << 32)
               | (unsigned)(s | (d << 16));
    }
}

// Fused node transforms via MFMA: 16 nodes per wave.
//  kx = x@Wk+bk (f32), qv = pack(bf16(x@Wq+bq), bf16(x@Wv+bv)), out = x@Wskip+bias
__device__ __forceinline__ void mat_mm(const unsigned short* __restrict__ WnT, int m,
                                       int lr, int lg, bf16x8 af0, bf16x8 af1,
                                       f32x4 acc[4]) {
#pragma unroll
    for (int h = 0; h < 4; ++h) {
        const bf16x8 b0 = *(const bf16x8*)(WnT + (size_t)(m * D + 16 * h + lr) * D + 8 * lg);
        const bf16x8 b1 = *(const bf16x8*)(WnT + (size_t)(m * D + 16 * h + lr) * D + 32 + 8 * lg);
        acc[h] = __builtin_amdgcn_mfma_f32_16x16x32_bf16(af0, b0, (f32x4)(0.f), 0, 0, 0);
        acc[h] = __builtin_amdgcn_mfma_f32_16x16x32_bf16(af1, b1, acc[h], 0, 0, 0);
    }
}

__global__ __launch_bounds__(256, 4)
void node_all(const float* __restrict__ x, const unsigned short* __restrict__ WnT,
              const float* __restrict__ bk, const float* __restrict__ bq,
              const float* __restrict__ bv, const float* __restrict__ bias,
              float* __restrict__ kx, unsigned* __restrict__ qv, float* __restrict__ out) {
    const int lane = threadIdx.x & 63;
    const int wid  = blockIdx.x * 4 + (threadIdx.x >> 6);
    if (wid >= NWN) return;
    const int lg = lane >> 4, lr = lane & 15;
    const int n0 = wid * 16;

    // A-frags: lane holds x[n0+lr][k], k = 32t + 8lg + e
    const float* xp = x + (size_t)(n0 + lr) * D + 8 * lg;
    const f32x4 x00 = *(const f32x4*)xp;
    const f32x4 x01 = *(const f32x4*)(xp + 4);
    const f32x4 x10 = *(const f32x4*)(xp + 32);
    const f32x4 x11 = *(const f32x4*)(xp + 36);
    bf16x8 af0, af1;
#pragma unroll
    for (int e = 0; e < 4; ++e) {
        af0[e] = f2bf(x00[e]); af0[e + 4] = f2bf(x01[e]);
        af1[e] = f2bf(x10[e]); af1[e + 4] = f2bf(x11[e]);
    }

    float bkv[4], bqv[4], bvv[4], bsv[4];
#pragma unroll
    for (int h = 0; h < 4; ++h) {
        bkv[h] = bk[16 * h + lr];
        bqv[h] = bq[16 * h + lr];
        bvv[h] = bv[16 * h + lr];
        bsv[h] = bias[16 * h + lr];
    }

    // C layout: lane (lg,lr) holds rows n0+4lg+r, col 16h+lr
    f32x4 acc[4];

    mat_mm(WnT, 0, lr, lg, af0, af1, acc);               // skip
#pragma unroll
    for (int r = 0; r < 4; ++r)
#pragma unroll
        for (int h = 0; h < 4; ++h)
            out[(size_t)(n0 + 4 * lg + r) * D + 16 * h + lr] = acc[h][r] + bsv[h];

    mat_mm(WnT, 1, lr, lg, af0, af1, acc);               // key
#pragma unroll
    for (int r = 0; r < 4; ++r)
#pragma unroll
        for (int h = 0; h < 4; ++h)
            kx[(size_t)(n0 + 4 * lg + r) * D + 16 * h + lr] = acc[h][r] + bkv[h];

    f32x4 accQ[4];
    mat_mm(WnT, 2, lr, lg, af0, af1, accQ);              // query
    mat_mm(WnT, 3, lr, lg, af0, af1, acc);               // value
#pragma unroll
    for (int r = 0; r < 4; ++r)
#pragma unroll
        for (int h = 0; h < 4; ++h)
            qv[(size_t)(n0 + 4 * lg + r) * D + 16 * h + lr] =
                packqv(accQ[h][r] + bqv[h], acc[h][r] + bvv[h]);
}

// Edge-parallel aggregation over dst-SORTED edges (unchanged from round 7).
__global__ __launch_bounds__(256, 3)
void agg_sorted(const unsigned* __restrict__ rec, const float* __restrict__ ea,
                const unsigned short* __restrict__ WgT, const unsigned short* __restrict__ WvT,
                const float* __restrict__ kx, const unsigned* __restrict__ qv,
                float* __restrict__ out) {
    const int lane = threadIdx.x & 63;
    const int wid  = blockIdx.x * 4 + (threadIdx.x >> 6);   // tile id, grid exact
    const int lg = lane >> 4;       // k-block (A,B) / row-group (C)
    const int lr = lane & 15;       // row (A) / col (B, C)
    const int e0 = wid * 64;

    bf16x8 bg[4], bvf[4];
#pragma unroll
    for (int h = 0; h < 4; ++h) {
        bg[h]  = *(const bf16x8*)(WgT + (size_t)(16 * h + lr) * ED + 8 * lg);
        bvf[h] = *(const bf16x8*)(WvT + (size_t)(16 * h + lr) * ED + 8 * lg);
    }

#pragma unroll
    for (int g = 0; g < 4; ++g) {
        const int gb = e0 + 16 * g;
        const uint4v rA = *(const uint4v*)(rec + 2 * (gb + 4 * lg));
        const uint4v rB = *(const uint4v*)(rec + 2 * (gb + 4 * lg) + 4);
        int dR[4], sR[4];
        dR[0] = (int)(rA.x >> 16); sR[0] = (int)(rA.x & 0xFFFFu);
        dR[1] = (int)(rA.z >> 16); sR[1] = (int)(rA.z & 0xFFFFu);
        dR[2] = (int)(rB.x >> 16); sR[2] = (int)(rB.x & 0xFFFFu);
        dR[3] = (int)(rB.z >> 16); sR[3] = (int)(rB.z & 0xFFFFu);

        const unsigned pl = rec[2 * (gb + lr) + 1];
        const float* ap = ea + (size_t)pl * ED + 8 * lg;
        const f32x4 a0 = __builtin_nontemporal_load((const f32x4*)ap);
        const f32x4 a1 = __builtin_nontemporal_load((const f32x4*)(ap + 4));

        unsigned qg[4][4];
        float    kk[4][4];
#pragma unroll
        for (int r = 0; r < 4; ++r) {
            const unsigned* qp = qv + (size_t)sR[r] * D;
            const float*    kp = kx + (size_t)dR[r] * D;
#pragma unroll
            for (int h = 0; h < 4; ++h) {
                qg[r][h] = qp[16 * h + lr];
                kk[r][h] = kp[16 * h + lr];
            }
        }

        bf16x8 af;
#pragma unroll
        for (int e2 = 0; e2 < 4; ++e2) { af[e2] = f2bf(a0[e2]); af[e2 + 4] = f2bf(a1[e2]); }

        f32x4 accG[4], accV[4];
#pragma unroll
        for (int h = 0; h < 4; ++h) {
            accG[h] = __builtin_amdgcn_mfma_f32_16x16x32_bf16(af, bg[h],  (f32x4)(0.f), 0, 0, 0);
            accV[h] = __builtin_amdgcn_mfma_f32_16x16x32_bf16(af, bvf[h], (f32x4)(0.f), 0, 0, 0);
        }

        float msg[4][4];
#pragma unroll
        for (int r = 0; r < 4; ++r)
#pragma unroll
            for (int h = 0; h < 4; ++h) {
                const float z = accG[h][r] + kk[r][h] + bflo2f(qg[r][h]);
                const float v = accV[h][r] + bfhi2f(qg[r][h]);
                msg[r][h] = v * __builtin_amdgcn_rcpf(1.0f + __expf(-z));
            }

        bool done[4] = {false, false, false, false};
        while (true) {
            int m0 = 0x7FFFFFFF;
#pragma unroll
            for (int r = 0; r < 4; ++r) m0 = min(m0, done[r] ? 0x7FFFFFFF : dR[r]);
            m0 = min(m0, __shfl_xor(m0, 16, 64));
            m0 = min(m0, __shfl_xor(m0, 32, 64));
            if (m0 == 0x7FFFFFFF) break;          // wave-uniform exit
            float sh[4];
#pragma unroll
            for (int h = 0; h < 4; ++h) {
                float a = 0.f;
#pragma unroll
                for (int r = 0; r < 4; ++r) a += (dR[r] == m0) ? msg[r][h] : 0.f;
                a += __shfl_xor(a, 16, 64);
                a += __shfl_xor(a, 32, 64);
                sh[h] = a;
            }
#pragma unroll
            for (int r = 0; r < 4; ++r) done[r] = done[r] || (dR[r] == m0);
            if (lane < 16) {
                float* op = out + (size_t)m0 * D;
#pragma unroll
                for (int h = 0; h < 4; ++h)
                    unsafeAtomicAdd(&op[16 * h + lane], sh[h]);
            }
        }
    }
}

extern "C" void kernel_launch(void* const* d_in, const int* in_sizes, int n_in,
                              void* d_out, int out_size, void* d_ws, size_t ws_size,
                              hipStream_t stream) {
    const float* x    = (const float*)d_in[0];
    const int*   eidx = (const int*)d_in[1];      // [2, E]: row0=src, row1=dst
    const float* eatt = (const float*)d_in[2];
    const float* Wk   = (const float*)d_in[3];
    const float* bk   = (const float*)d_in[4];
    const float* Wq   = (const float*)d_in[5];
    const float* bq   = (const float*)d_in[6];
    const float* Wv   = (const float*)d_in[7];
    const float* bv   = (const float*)d_in[8];
    const float* Ws   = (const float*)d_in[9];
    const float* bias = (const float*)d_in[10];
    float* out = (float*)d_out;

    // workspace carve (offsets keep 16B alignment)
    char* w = (char*)d_ws;
    float*    kx  = (float*)w;            w += (size_t)NN * D * 4;   // 12.8 MB
    unsigned* qv  = (unsigned*)w;         w += (size_t)NN * D * 4;   // 12.8 MB
    unsigned short* WnT = (unsigned short*)w;  w += 4 * D * D * 2;   // 32 KB
    unsigned short* WgT = (unsigned short*)w;  w += D * ED * 2;      // 4 KB
    unsigned short* WvT = (unsigned short*)w;  w += D * ED * 2;      // 4 KB
    int* deg  = (int*)w;                  w += (size_t)NN * 4;       // 200 KB
    int* off  = (int*)w;                  w += (size_t)NN * 4;       // 200 KB
    int* bsum = (int*)w;                  w += 256 * 4;              // 1 KB
    unsigned long long* rec = (unsigned long long*)w;                // 6.4 MB

    const int* srcI = eidx;
    const int* dstI = eidx + EE;
    const int NB = (NN + 255) / 256;   // 196

    prep_w<<<(4 * D * D + D * ED + 255) / 256, 256, 0, stream>>>(Wk, Wq, Wv, Ws,
                                                                 WnT, WgT, WvT);

    // CSR-order build
    hipMemsetAsync(deg, 0, (size_t)NN * 4, stream);
    k_hist<<<EE / 256, 256, 0, stream>>>(dstI, deg);
    k_scanA<<<NB, 256, 0, stream>>>(deg, off, bsum);
    k_scanB<<<1, 256, 0, stream>>>(bsum, NB);
    k_scanC<<<NB, 256, 0, stream>>>(off, bsum);
    k_scatter<<<EE / 256, 256, 0, stream>>>(srcI, dstI, off, rec);

    // fused MFMA node transforms: 3125 waves = 782 blocks
    node_all<<<(NWN + 3) / 4, 256, 0, stream>>>(x, WnT, bk, bq, bv, bias,
                                                kx, qv, out);

    // edge-parallel aggregation over sorted records: 12500 waves = 3125 blocks
    agg_sorted<<<NT64 / 4, 256, 0, stream>>>((const unsigned*)rec, eatt,
                                             WgT, WvT, kx, qv, out);
}

// Round 9
// 176.572 us; speedup vs baseline: 1.5126x; 1.0811x over previous
//
#include <hip/hip_runtime.h>
#include <hip/hip_bf16.h>

#define D 64
#define ED 32
#define NN 50000
#define EE 800000
#define NT64 (EE / 64)   // 12500 64-edge tiles, exact
#define NWN (NN / 16)    // 3125 16-node tiles, exact

#define PREP_N (4 * D * D + D * ED)          // 18432 prep elements
#define NB_PREP ((PREP_N + 255) / 256)       // 72
#define NB_ZERO ((NN / 4 + 255) / 256)       // 49  (NN % 4 == 0)
#define NB_NODE ((NWN + 3) / 4)              // 782
#define NB_HIST ((EE / 4 + 255) / 256)       // 782 (EE % 4 == 0)
#define NB_SCAN ((NN + 255) / 256)           // 196

typedef __attribute__((ext_vector_type(8))) short bf16x8;
typedef __attribute__((ext_vector_type(4))) float f32x4;
typedef __attribute__((ext_vector_type(4))) unsigned uint4v;
typedef __attribute__((ext_vector_type(4))) int int4v;

__device__ __forceinline__ short f2bf(float f) {
    __hip_bfloat16 h = __float2bfloat16(f);
    return *reinterpret_cast<short*>(&h);
}
__device__ __forceinline__ float bfhi2f(unsigned w) { return __uint_as_float(w & 0xFFFF0000u); }
__device__ __forceinline__ float bflo2f(unsigned w) { return __uint_as_float(w << 16); }
__device__ __forceinline__ unsigned packqv(float q, float v) {
    return (unsigned)(unsigned short)f2bf(q) | ((unsigned)(unsigned short)f2bf(v) << 16);
}

// Fused: weight prep (WnT node parts, WgT/WvT edge parts) + deg zeroing.
__global__ void prep_zero(const float* __restrict__ Wk, const float* __restrict__ Wq,
                          const float* __restrict__ Wv, const float* __restrict__ Ws,
                          unsigned short* __restrict__ WnT,
                          unsigned short* __restrict__ WgT, unsigned short* __restrict__ WvT,
                          int* __restrict__ deg) {
    const int b = blockIdx.x;
    if (b < NB_PREP) {
        const int i = b * 256 + threadIdx.x;
        if (i < 4 * D * D) {
            const int m = i >> 12, col = (i >> 6) & 63, k = i & 63;
            const float* W = (m == 0) ? Ws : (m == 1) ? Wk : (m == 2) ? Wq : Wv;
            WnT[i] = (unsigned short)f2bf(W[k * D + col]);
        } else {
            const int j = i - 4 * D * D;
            if (j < D * ED) {
                const int c = j >> 5, k = j & 31;
                const size_t off = (size_t)(D + k) * D + c;
                WgT[j] = (unsigned short)f2bf(Wk[off] + Wq[off]);
                WvT[j] = (unsigned short)f2bf(Wv[off]);
            }
        }
    } else {
        const int i = (b - NB_PREP) * 256 + threadIdx.x;   // int4 index
        if (i < NN / 4) ((int4v*)deg)[i] = (int4v){0, 0, 0, 0};
    }
}

// Mega-kernel: node transforms (MFMA) + dst histogram (independent work,
// partitioned by blockIdx; both only depend on prep_zero).
__global__ __launch_bounds__(256, 4)
void node_hist(const float* __restrict__ x, const unsigned short* __restrict__ WnT,
               const float* __restrict__ bk, const float* __restrict__ bq,
               const float* __restrict__ bv, const float* __restrict__ bias,
               float* __restrict__ kx, unsigned* __restrict__ qv, float* __restrict__ out,
               const int* __restrict__ dstI, int* __restrict__ deg) {
    const int b = blockIdx.x;
    if (b >= NB_NODE) {
        // ---- histogram: 4 edges per thread, int4 NT loads ----
        const int t = (b - NB_NODE) * 256 + threadIdx.x;
        const int e = 4 * t;
        if (e + 4 <= EE) {
            const int4v d4 = __builtin_nontemporal_load((const int4v*)(dstI + e));
#pragma unroll
            for (int r = 0; r < 4; ++r) atomicAdd(&deg[d4[r]], 1);
        }
        return;
    }
    // ---- node transforms: 16 nodes per wave ----
    const int lane = threadIdx.x & 63;
    const int wid  = b * 4 + (threadIdx.x >> 6);
    if (wid >= NWN) return;
    const int lg = lane >> 4, lr = lane & 15;
    const int n0 = wid * 16;

    const float* xp = x + (size_t)(n0 + lr) * D + 8 * lg;
    const f32x4 x00 = *(const f32x4*)xp;
    const f32x4 x01 = *(const f32x4*)(xp + 4);
    const f32x4 x10 = *(const f32x4*)(xp + 32);
    const f32x4 x11 = *(const f32x4*)(xp + 36);
    bf16x8 af0, af1;
#pragma unroll
    for (int e = 0; e < 4; ++e) {
        af0[e] = f2bf(x00[e]); af0[e + 4] = f2bf(x01[e]);
        af1[e] = f2bf(x10[e]); af1[e + 4] = f2bf(x11[e]);
    }

    float bkv[4], bqv[4], bvv[4], bsv[4];
#pragma unroll
    for (int h = 0; h < 4; ++h) {
        bkv[h] = bk[16 * h + lr];
        bqv[h] = bq[16 * h + lr];
        bvv[h] = bv[16 * h + lr];
        bsv[h] = bias[16 * h + lr];
    }

    f32x4 acc[4], accQ[4];
#pragma unroll
    for (int m = 0; m < 4; ++m) {
        f32x4* A = (m == 2) ? accQ : acc;
#pragma unroll
        for (int h = 0; h < 4; ++h) {
            const bf16x8 b0 = *(const bf16x8*)(WnT + (size_t)(m * D + 16 * h + lr) * D + 8 * lg);
            const bf16x8 b1 = *(const bf16x8*)(WnT + (size_t)(m * D + 16 * h + lr) * D + 32 + 8 * lg);
            A[h] = __builtin_amdgcn_mfma_f32_16x16x32_bf16(af0, b0, (f32x4)(0.f), 0, 0, 0);
            A[h] = __builtin_amdgcn_mfma_f32_16x16x32_bf16(af1, b1, A[h], 0, 0, 0);
        }
        if (m == 0) {
#pragma unroll
            for (int r = 0; r < 4; ++r)
#pragma unroll
                for (int h = 0; h < 4; ++h)
                    out[(size_t)(n0 + 4 * lg + r) * D + 16 * h + lr] = acc[h][r] + bsv[h];
        } else if (m == 1) {
#pragma unroll
            for (int r = 0; r < 4; ++r)
#pragma unroll
                for (int h = 0; h < 4; ++h)
                    kx[(size_t)(n0 + 4 * lg + r) * D + 16 * h + lr] = acc[h][r] + bkv[h];
        } else if (m == 3) {
#pragma unroll
            for (int r = 0; r < 4; ++r)
#pragma unroll
                for (int h = 0; h < 4; ++h)
                    qv[(size_t)(n0 + 4 * lg + r) * D + 16 * h + lr] =
                        packqv(accQ[h][r] + bqv[h], acc[h][r] + bvv[h]);
        }
    }
}

// Block-local exclusive scan of deg (256 nodes/block) + per-block totals.
__global__ void k_scanA(const int* __restrict__ deg, int* __restrict__ off,
                        int* __restrict__ bsum) {
    __shared__ int tmp[256];
    const int t = threadIdx.x, i = blockIdx.x * 256 + t;
    const int v = (i < NN) ? deg[i] : 0;
    tmp[t] = v;
    __syncthreads();
    for (int d = 1; d < 256; d <<= 1) {
        const int add = (t >= d) ? tmp[t - d] : 0;
        __syncthreads();
        tmp[t] += add;
        __syncthreads();
    }
    if (i < NN) off[i] = tmp[t] - v;          // block-local exclusive
    if (t == 255) bsum[blockIdx.x] = tmp[255];
}

// Exclusive scan of the 196 block totals (single block).
__global__ void k_scanB(int* __restrict__ bsum, int nb) {
    __shared__ int tmp[256];
    const int t = threadIdx.x;
    const int v = (t < nb) ? bsum[t] : 0;
    tmp[t] = v;
    __syncthreads();
    for (int d = 1; d < 256; d <<= 1) {
        const int add = (t >= d) ? tmp[t - d] : 0;
        __syncthreads();
        tmp[t] += add;
        __syncthreads();
    }
    if (t < nb) bsum[t] = tmp[t] - v;         // exclusive, in place
}

// Scatter, 4 edges/thread; global position = bsum[d>>8] + fetch-add on
// block-local off (folds the old scanC pass into the address calc).
__global__ void k_scatter4(const int* __restrict__ srcI, const int* __restrict__ dstI,
                           int* __restrict__ off, const int* __restrict__ bsum,
                           unsigned long long* __restrict__ rec) {
    const int t = blockIdx.x * 256 + threadIdx.x;
    const int e = 4 * t;
    if (e + 4 > EE) return;
    const int4v s4 = __builtin_nontemporal_load((const int4v*)(srcI + e));
    const int4v d4 = __builtin_nontemporal_load((const int4v*)(dstI + e));
#pragma unroll
    for (int r = 0; r < 4; ++r) {
        const int s = s4[r], d = d4[r];
        const int p = bsum[d >> 8] + atomicAdd(&off[d], 1);
        rec[p] = ((unsigned long long)(unsigned)(e + r) << 32)
               | (unsigned)(s | (d << 16));
    }
}

// Edge-parallel aggregation over dst-SORTED edges (unchanged, proven).
__global__ __launch_bounds__(256, 3)
void agg_sorted(const unsigned* __restrict__ rec, const float* __restrict__ ea,
                const unsigned short* __restrict__ WgT, const unsigned short* __restrict__ WvT,
                const float* __restrict__ kx, const unsigned* __restrict__ qv,
                float* __restrict__ out) {
    const int lane = threadIdx.x & 63;
    const int wid  = blockIdx.x * 4 + (threadIdx.x >> 6);   // tile id, grid exact
    const int lg = lane >> 4;
    const int lr = lane & 15;
    const int e0 = wid * 64;

    bf16x8 bg[4], bvf[4];
#pragma unroll
    for (int h = 0; h < 4; ++h) {
        bg[h]  = *(const bf16x8*)(WgT + (size_t)(16 * h + lr) * ED + 8 * lg);
        bvf[h] = *(const bf16x8*)(WvT + (size_t)(16 * h + lr) * ED + 8 * lg);
    }

#pragma unroll
    for (int g = 0; g < 4; ++g) {
        const int gb = e0 + 16 * g;
        const uint4v rA = *(const uint4v*)(rec + 2 * (gb + 4 * lg));
        const uint4v rB = *(const uint4v*)(rec + 2 * (gb + 4 * lg) + 4);
        int dR[4], sR[4];
        dR[0] = (int)(rA.x >> 16); sR[0] = (int)(rA.x & 0xFFFFu);
        dR[1] = (int)(rA.z >> 16); sR[1] = (int)(rA.z & 0xFFFFu);
        dR[2] = (int)(rB.x >> 16); sR[2] = (int)(rB.x & 0xFFFFu);
        dR[3] = (int)(rB.z >> 16); sR[3] = (int)(rB.z & 0xFFFFu);

        const unsigned pl = rec[2 * (gb + lr) + 1];
        const float* ap = ea + (size_t)pl * ED + 8 * lg;
        const f32x4 a0 = __builtin_nontemporal_load((const f32x4*)ap);
        const f32x4 a1 = __builtin_nontemporal_load((const f32x4*)(ap + 4));

        unsigned qg[4][4];
        float    kk[4][4];
#pragma unroll
        for (int r = 0; r < 4; ++r) {
            const unsigned* qp = qv + (size_t)sR[r] * D;
            const float*    kp = kx + (size_t)dR[r] * D;
#pragma unroll
            for (int h = 0; h < 4; ++h) {
                qg[r][h] = qp[16 * h + lr];
                kk[r][h] = kp[16 * h + lr];
            }
        }

        bf16x8 af;
#pragma unroll
        for (int e2 = 0; e2 < 4; ++e2) { af[e2] = f2bf(a0[e2]); af[e2 + 4] = f2bf(a1[e2]); }

        f32x4 accG[4], accV[4];
#pragma unroll
        for (int h = 0; h < 4; ++h) {
            accG[h] = __builtin_amdgcn_mfma_f32_16x16x32_bf16(af, bg[h],  (f32x4)(0.f), 0, 0, 0);
            accV[h] = __builtin_amdgcn_mfma_f32_16x16x32_bf16(af, bvf[h], (f32x4)(0.f), 0, 0, 0);
        }

        float msg[4][4];
#pragma unroll
        for (int r = 0; r < 4; ++r)
#pragma unroll
            for (int h = 0; h < 4; ++h) {
                const float z = accG[h][r] + kk[r][h] + bflo2f(qg[r][h]);
                const float v = accV[h][r] + bfhi2f(qg[r][h]);
                msg[r][h] = v * __builtin_amdgcn_rcpf(1.0f + __expf(-z));
            }

        bool done[4] = {false, false, false, false};
        while (true) {
            int m0 = 0x7FFFFFFF;
#pragma unroll
            for (int r = 0; r < 4; ++r) m0 = min(m0, done[r] ? 0x7FFFFFFF : dR[r]);
            m0 = min(m0, __shfl_xor(m0, 16, 64));
            m0 = min(m0, __shfl_xor(m0, 32, 64));
            if (m0 == 0x7FFFFFFF) break;          // wave-uniform exit
            float sh[4];
#pragma unroll
            for (int h = 0; h < 4; ++h) {
                float a = 0.f;
#pragma unroll
                for (int r = 0; r < 4; ++r) a += (dR[r] == m0) ? msg[r][h] : 0.f;
                a += __shfl_xor(a, 16, 64);
                a += __shfl_xor(a, 32, 64);
                sh[h] = a;
            }
#pragma unroll
            for (int r = 0; r < 4; ++r) done[r] = done[r] || (dR[r] == m0);
            if (lane < 16) {
                float* op = out + (size_t)m0 * D;
#pragma unroll
                for (int h = 0; h < 4; ++h)
                    unsafeAtomicAdd(&op[16 * h + lane], sh[h]);
            }
        }
    }
}

extern "C" void kernel_launch(void* const* d_in, const int* in_sizes, int n_in,
                              void* d_out, int out_size, void* d_ws, size_t ws_size,
                              hipStream_t stream) {
    const float* x    = (const float*)d_in[0];
    const int*   eidx = (const int*)d_in[1];      // [2, E]: row0=src, row1=dst
    const float* eatt = (const float*)d_in[2];
    const float* Wk   = (const float*)d_in[3];
    const float* bk   = (const float*)d_in[4];
    const float* Wq   = (const float*)d_in[5];
    const float* bq   = (const float*)d_in[6];
    const float* Wv   = (const float*)d_in[7];
    const float* bv   = (const float*)d_in[8];
    const float* Ws   = (const float*)d_in[9];
    const float* bias = (const float*)d_in[10];
    float* out = (float*)d_out;

    // workspace carve (offsets keep 16B alignment)
    char* w = (char*)d_ws;
    float*    kx  = (float*)w;            w += (size_t)NN * D * 4;   // 12.8 MB
    unsigned* qv  = (unsigned*)w;         w += (size_t)NN * D * 4;   // 12.8 MB
    unsigned short* WnT = (unsigned short*)w;  w += 4 * D * D * 2;   // 32 KB
    unsigned short* WgT = (unsigned short*)w;  w += D * ED * 2;      // 4 KB
    unsigned short* WvT = (unsigned short*)w;  w += D * ED * 2;      // 4 KB
    int* deg  = (int*)w;                  w += (size_t)NN * 4;       // 200 KB
    int* off  = (int*)w;                  w += (size_t)NN * 4;       // 200 KB
    int* bsum = (int*)w;                  w += 256 * 4;              // 1 KB
    unsigned long long* rec = (unsigned long long*)w;                // 6.4 MB

    const int* srcI = eidx;
    const int* dstI = eidx + EE;

    // 1) weight prep + deg zeroing (independent halves, one launch)
    prep_zero<<<NB_PREP + NB_ZERO, 256, 0, stream>>>(Wk, Wq, Wv, Ws,
                                                     WnT, WgT, WvT, deg);
    // 2) node transforms (needs WnT) + histogram (needs deg zeroed)
    node_hist<<<NB_NODE + NB_HIST, 256, 0, stream>>>(x, WnT, bk, bq, bv, bias,
                                                     kx, qv, out, dstI, deg);
    // 3,4) two-level exclusive scan
    k_scanA<<<NB_SCAN, 256, 0, stream>>>(deg, off, bsum);
    k_scanB<<<1, 256, 0, stream>>>(bsum, NB_SCAN);
    // 5) scatter into dst-sorted records (scanC folded into address calc)
    k_scatter4<<<NB_HIST, 256, 0, stream>>>(srcI, dstI, off, bsum, rec);
    // 6) aggregation
    agg_sorted<<<NT64 / 4, 256, 0, stream>>>((const unsigned*)rec, eatt,
                                             WgT, WvT, kx, qv, out);
}